// Round 1
// baseline (1100.499 us; speedup 1.0000x reference)
//
#include <hip/hip_runtime.h>
#include <hip/hip_bf16.h>
#include <math.h>

#define DIM   160
#define NVOX  (160*160*160)       // 4,096,000 voxels per volume
#define TILE  16
#define ZCHUNK 40
#define NZC    4                  // 4 z-chunks * 40 = 160

// ---------------------------------------------------------------------------
// init: bufA[0..1] = fg (softmax ch1) per batch, bufA[2..3] = tg (target==1)
// ---------------------------------------------------------------------------
__global__ __launch_bounds__(256) void init_vols(const float* __restrict__ net,
                                                 const int* __restrict__ tgt,
                                                 float* __restrict__ bufA) {
    const int v = blockIdx.y;                       // volume 0..3
    const int i = (blockIdx.x * 256 + threadIdx.x) * 4;
    if (i >= NVOX) return;
    float4 o;
    if (v < 2) {
        const float4 x0 = *(const float4*)(net + ((size_t)(v * 2 + 0) * NVOX + i));
        const float4 x1 = *(const float4*)(net + ((size_t)(v * 2 + 1) * NVOX + i));
        o.x = 1.0f / (1.0f + expf(x0.x - x1.x));
        o.y = 1.0f / (1.0f + expf(x0.y - x1.y));
        o.z = 1.0f / (1.0f + expf(x0.z - x1.z));
        o.w = 1.0f / (1.0f + expf(x0.w - x1.w));
    } else {
        const int4 tv = *(const int4*)(tgt + ((size_t)(v - 2) * NVOX + i));
        o.x = (tv.x == 1) ? 1.0f : 0.0f;
        o.y = (tv.y == 1) ? 1.0f : 0.0f;
        o.z = (tv.z == 1) ? 1.0f : 0.0f;
        o.w = (tv.w == 1) ? 1.0f : 0.0f;
    }
    *(float4*)(bufA + (size_t)v * NVOX + i) = o;
}

// ---------------------------------------------------------------------------
// one skeletonization iteration, fused:
//   minp = minpool3(x)  (valid-only, +inf pad)
//   contour = relu(maxpool3(minp) - minp)   (valid-only, -inf pad)
//   x' = relu(x - contour)
// z-plane-sweep: per output plane zo we need x(zo), m(zo) and B(zo-1..zo+1)
// where A(z)=2D 3x3 min of x-plane z, m(z)=min(A(z-1..z+1)) (+boundary -inf),
// B(z)=2D 3x3 max of m-plane z.
// ---------------------------------------------------------------------------
__global__ __launch_bounds__(256) void sweep(const float* __restrict__ src,
                                             float* __restrict__ dst) {
    __shared__ float xs[3][20][20];   // x planes, halo 2          (rows pad 20)
    __shared__ float rm[20][20];      // rowmin / rowmax scratch
    __shared__ float As[3][18][20];   // 2D-min planes, halo 1
    __shared__ float ms[2][18][20];   // 3D-min planes, halo 1
    __shared__ float Bs[3][16][16];   // 2D-max-of-m planes (tile only)

    const int t   = threadIdx.x;
    const int tx  = t & 15, ty = t >> 4;
    const int bx  = blockIdx.x;                  // 0..99
    const int tx0 = (bx % 10) * TILE;
    const int ty0 = (bx / 10) * TILE;
    const int zbeg = blockIdx.y * ZCHUNK;
    const int zend = zbeg + ZCHUNK;
    const float* sv = src + (size_t)blockIdx.z * NVOX;
    float*       dv = dst + (size_t)blockIdx.z * NVOX;
    const int mlo = (zbeg == 0) ? 0 : (zbeg - 1); // first m/B plane we need

    for (int zo = zbeg - 4; zo < zend; ++zo) {
        // ---- stage L: load x plane zl = zo+2 (halo 2, +inf outside volume)
        const int zl = zo + 2;
        const int sl = (zl + 6) % 3;
        for (int i = t; i < 400; i += 256) {
            const int r = i / 20, c = i - r * 20;
            const int gy = ty0 + r - 2, gx = tx0 + c - 2;
            float v = INFINITY;
            if ((unsigned)zl < 160u && (unsigned)gy < 160u && (unsigned)gx < 160u)
                v = sv[(zl * 160 + gy) * 160 + gx];
            (&xs[sl][0][0])[i] = v;
        }
        __syncthreads();

        // ---- stage A1: rowmin of xs plane  (20 rows x 18 cols)
        if (t < 180) {
            const int r = t / 9, c2 = (t - r * 9) * 2;
            const float* xr = &xs[sl][r][0];
            const float a0 = xr[c2], a1 = xr[c2 + 1], a2 = xr[c2 + 2], a3 = xr[c2 + 3];
            rm[r][c2]     = fminf(fminf(a0, a1), a2);
            rm[r][c2 + 1] = fminf(fminf(a1, a2), a3);
        }
        __syncthreads();

        // ---- stage A2+m: colmin -> A(zl); m(zm)=min(A(zm-1),A(zm),A(zm+1)), zm=zo+1
        const int zm = zo + 1;
        const bool do_m = (zm >= mlo) && (zm < 160);
        {
            const int smA  = (zm + 6) % 3;    // A(zm)
            const int smA0 = (zm + 5) % 3;    // A(zm-1)
            if (t < 162) {
                const int r = t / 9, c2 = (t - r * 9) * 2;
#pragma unroll
                for (int k = 0; k < 2; ++k) {
                    const int c = c2 + k;
                    const float a = fminf(fminf(rm[r][c], rm[r + 1][c]), rm[r + 2][c]);
                    As[sl][r][c] = a;
                    if (do_m) {
                        float mv = fminf(a, fminf(As[smA][r][c], As[smA0][r][c]));
                        const int gy = ty0 + r - 1, gx = tx0 + c - 1;
                        if ((unsigned)gy >= 160u || (unsigned)gx >= 160u) mv = -INFINITY;
                        ms[zm & 1][r][c] = mv;
                    }
                }
            }
        }
        __syncthreads();

        // ---- stage B1: rowmax of m plane zm  (18 rows x 16 cols) into rm
        if (do_m && t < 144) {
            const int r = t / 8, c2 = (t - r * 8) * 2;
            const float* mr = &ms[zm & 1][r][0];
            const float a0 = mr[c2], a1 = mr[c2 + 1], a2 = mr[c2 + 2], a3 = mr[c2 + 3];
            rm[r][c2]     = fmaxf(fmaxf(a0, a1), a2);
            rm[r][c2 + 1] = fmaxf(fmaxf(a1, a2), a3);
        }
        __syncthreads();

        // ---- stage B2: colmax -> B(zm); fused output of plane zo
        float bv = -INFINITY;
        if (do_m) {
            bv = fmaxf(fmaxf(rm[ty][tx], rm[ty + 1][tx]), rm[ty + 2][tx]);
            Bs[(zm + 6) % 3][ty][tx] = bv;
        }
        if (zo >= zbeg) {
            float cmax = bv;                                        // B(zo+1) or -inf
            cmax = fmaxf(cmax, Bs[(zo + 6) % 3][ty][tx]);           // B(zo)
            if (zo > 0) cmax = fmaxf(cmax, Bs[(zo + 5) % 3][ty][tx]); // B(zo-1)
            const float mc = ms[zo & 1][ty + 1][tx + 1];            // minp at p
            const float xc = xs[(zo + 6) % 3][ty + 2][tx + 2];      // x at p
            const float contour = fmaxf(cmax - mc, 0.0f);
            dv[(zo * 160 + ty0 + ty) * 160 + tx0 + tx] = fmaxf(xc - contour, 0.0f);
        }
        __syncthreads();   // protect xs/ms/Bs/rm slot reuse next step
    }
}

// ---------------------------------------------------------------------------
// reductions: per batch b
//   acc[b*4+0] = sum(skel_fg)          acc[b*4+1] = sum(skel_fg * tg)
//   acc[b*4+2] = sum(skel_tg)          acc[b*4+3] = sum(skel_tg * fg)
// fg/tg recomputed on the fly from inputs.
// ---------------------------------------------------------------------------
__global__ __launch_bounds__(256) void reduce_sums(const float* __restrict__ skel,
                                                   const float* __restrict__ net,
                                                   const int* __restrict__ tgt,
                                                   float* __restrict__ acc) {
    const int b = blockIdx.y;
    const float* skf = skel + (size_t)b * NVOX;
    const float* skt = skel + (size_t)(2 + b) * NVOX;
    const float* n0  = net + (size_t)(b * 2 + 0) * NVOX;
    const float* n1  = net + (size_t)(b * 2 + 1) * NVOX;
    const int*   tb  = tgt + (size_t)b * NVOX;

    float s_o = 0.f, s_ot = 0.f, s_t = 0.f, s_tf = 0.f;
    for (int i = (blockIdx.x * 256 + threadIdx.x) * 4; i < NVOX; i += gridDim.x * 1024) {
        const float4 sf = *(const float4*)(skf + i);
        const float4 st = *(const float4*)(skt + i);
        const float4 x0 = *(const float4*)(n0 + i);
        const float4 x1 = *(const float4*)(n1 + i);
        const int4   tv = *(const int4*)(tb + i);
        {
            const float tg = (tv.x == 1) ? 1.f : 0.f;
            const float fg = 1.f / (1.f + expf(x0.x - x1.x));
            s_o += sf.x; s_ot += sf.x * tg; s_t += st.x; s_tf += st.x * fg;
        }
        {
            const float tg = (tv.y == 1) ? 1.f : 0.f;
            const float fg = 1.f / (1.f + expf(x0.y - x1.y));
            s_o += sf.y; s_ot += sf.y * tg; s_t += st.y; s_tf += st.y * fg;
        }
        {
            const float tg = (tv.z == 1) ? 1.f : 0.f;
            const float fg = 1.f / (1.f + expf(x0.z - x1.z));
            s_o += sf.z; s_ot += sf.z * tg; s_t += st.z; s_tf += st.z * fg;
        }
        {
            const float tg = (tv.w == 1) ? 1.f : 0.f;
            const float fg = 1.f / (1.f + expf(x0.w - x1.w));
            s_o += sf.w; s_ot += sf.w * tg; s_t += st.w; s_tf += st.w * fg;
        }
    }
#pragma unroll
    for (int off = 32; off > 0; off >>= 1) {
        s_o  += __shfl_down(s_o,  off);
        s_ot += __shfl_down(s_ot, off);
        s_t  += __shfl_down(s_t,  off);
        s_tf += __shfl_down(s_tf, off);
    }
    __shared__ float part[4][4];
    const int wave = threadIdx.x >> 6, lane = threadIdx.x & 63;
    if (lane == 0) { part[0][wave] = s_o; part[1][wave] = s_ot; part[2][wave] = s_t; part[3][wave] = s_tf; }
    __syncthreads();
    if (threadIdx.x == 0) {
        atomicAdd(&acc[b * 4 + 0], part[0][0] + part[0][1] + part[0][2] + part[0][3]);
        atomicAdd(&acc[b * 4 + 1], part[1][0] + part[1][1] + part[1][2] + part[1][3]);
        atomicAdd(&acc[b * 4 + 2], part[2][0] + part[2][1] + part[2][2] + part[2][3]);
        atomicAdd(&acc[b * 4 + 3], part[3][0] + part[3][1] + part[3][2] + part[3][3]);
    }
}

__global__ void zero_acc(float* acc) {
    if (threadIdx.x < 8) acc[threadIdx.x] = 0.f;
}

__global__ void finalize(const float* __restrict__ acc, float* __restrict__ out) {
    if (threadIdx.x == 0) {
        const float i0 = (acc[1] + 1.f) / (acc[0] + 1.f);
        const float t0 = (acc[3] + 1.f) / (acc[2] + 1.f);
        const float i1 = (acc[5] + 1.f) / (acc[4] + 1.f);
        const float t1 = (acc[7] + 1.f) / (acc[6] + 1.f);
        const float inter = i0 * t0 + i1 * t1;
        out[0] = -(2.f * inter / ((i0 + i1) + (t0 + t1)));
    }
}

// ---------------------------------------------------------------------------
extern "C" void kernel_launch(void* const* d_in, const int* in_sizes, int n_in,
                              void* d_out, int out_size, void* d_ws, size_t ws_size,
                              hipStream_t stream) {
    const float* net = (const float*)d_in[0];   // (2,2,160,160,160) f32
    const int*   tgt = (const int*)d_in[1];     // (2,1,160,160,160) int
    float* bufA = (float*)d_ws;                 // 4 volumes
    float* bufB = bufA + (size_t)4 * NVOX;      // 4 volumes
    float* acc  = bufB + (size_t)4 * NVOX;      // 8 floats

    zero_acc<<<1, 64, 0, stream>>>(acc);
    init_vols<<<dim3(NVOX / 1024, 4), 256, 0, stream>>>(net, tgt, bufA);

    float* s = bufA;
    float* d = bufB;
    for (int it = 0; it < 10; ++it) {
        sweep<<<dim3(100, NZC, 4), 256, 0, stream>>>(s, d);
        float* tmp = s; s = d; d = tmp;
    }
    // 10 iterations (even) -> final skeletons back in bufA (== s)
    reduce_sums<<<dim3(1024, 2), 256, 0, stream>>>(s, net, tgt, acc);
    finalize<<<1, 64, 0, stream>>>(acc, (float*)d_out);
}

// Round 7
// 478.478 us; speedup vs baseline: 2.3000x; 2.3000x over previous
//
#include <hip/hip_runtime.h>
#include <math.h>

#define NVOX   (160*160*160)
#define ZCHUNK 20
#define NZC    8
#define FINF   INFINITY

__device__ __forceinline__ float min3(float a, float b, float c) { return fminf(a, fminf(b, c)); }
__device__ __forceinline__ float max3(float a, float b, float c) { return fmaxf(a, fmaxf(b, c)); }
__device__ __forceinline__ float sigd(float d) { return 1.0f / (1.0f + __expf(d)); }  // d = x0-x1

__device__ __forceinline__ void ld8(const float* p, float* o) {
    float4 a = *(const float4*)p; float4 b = *(const float4*)(p + 4);
    o[0]=a.x; o[1]=a.y; o[2]=a.z; o[3]=a.w; o[4]=b.x; o[5]=b.y; o[6]=b.z; o[7]=b.w;
}
__device__ __forceinline__ void st8(float* p, const float* o) {
    *(float4*)p       = make_float4(o[0], o[1], o[2], o[3]);
    *(float4*)(p + 4) = make_float4(o[4], o[5], o[6], o[7]);
}
__device__ __forceinline__ void ld8i(const int* p, float* o) {
    int4 a = *(const int4*)p; int4 b = *(const int4*)(p + 4);
    o[0]=(a.x==1)?1.f:0.f; o[1]=(a.y==1)?1.f:0.f; o[2]=(a.z==1)?1.f:0.f; o[3]=(a.w==1)?1.f:0.f;
    o[4]=(b.x==1)?1.f:0.f; o[5]=(b.y==1)?1.f:0.f; o[6]=(b.z==1)?1.f:0.f; o[7]=(b.w==1)?1.f:0.f;
}
__device__ __forceinline__ void ld8sig(const float* p0, const float* p1, float* o) {
    float a0[8], a1[8]; ld8(p0, a0); ld8(p1, a1);
#pragma unroll
    for (int k = 0; k < 8; ++k) o[k] = sigd(a0[k] - a1[k]);
}

// ---------------------------------------------------------------------------
// One skeletonization iteration.
//   minp = minpool3(x) (+inf SAME pad), contour = relu(maxpool3(minp)-minp)
//   (-inf SAME pad), x' = relu(x - contour).
// Block: 256 thr = 4 waves x (3 rows of 20 lanes, 4 idle). 12 thread-rows:
//   stage1 row-load map gy1 = (R==11)? Y0-2 : Y0-1+R  (covers Y0-2..Y0+9)
//   stage2: thread-row R (<10) computes m-row gym=Y0-1+R (reads rmbuf R..R+2)
//   stage4: rows 1..8 output row gym (own m & own x already in registers)
// x-direction pooling via lane shuffles (8 px/thread, edges overridden);
// z-direction via register pipelines (Ah/Bh/mh/xh); y via LDS b128 rows.
// Pipeline timing at step zo (before the end-of-loop shift):
//   xv = x(zo+2); xh2 = x(zo+1); xh1 = x(zo)      <- stage4 reads xh1
//   mh0 = m(zo); Bn = B(zo+1); Bh1 = B(zo); Bh0 = B(zo-1)
// SRC: 0 = read float volume, 1 = compute fg/tg from net/tgt (iteration 1)
// SINK: 0 = store volume,     1 = accumulate sums (iteration 10)
// ---------------------------------------------------------------------------
template<int SRC, int SINK>
__global__ __launch_bounds__(256, 2) void sweep(
        const float* __restrict__ src, float* __restrict__ dst,
        const float* __restrict__ net, const int* __restrict__ tgt,
        float* __restrict__ acc)
{
    __shared__ float rmbuf[12][172];   // rowmin-of-x rows   (gy = Y0-2+idx)
    __shared__ float bmx[10][172];     // rowmax-of-m rows   (gym = Y0-1+idx)
    __shared__ float red[2][4];

    const int vol  = blockIdx.z;
    const int Y0   = blockIdx.x * 8;
    const int zbeg = blockIdx.y * ZCHUNK;
    const int zend = zbeg + ZCHUNK;
    const int lane = threadIdx.x & 63;
    const int wv   = threadIdx.x >> 6;
    const int r3   = lane / 20;            // 0..2 active, 3 idle
    const int xt   = lane - r3 * 20;       // 0..19
    const int R    = wv * 3 + r3;          // 0..11
    const bool act = (r3 < 3);
    const int x0   = xt * 8;
    const int gy1  = (R == 11) ? (Y0 - 2) : (Y0 - 1 + R);
    const int ri   = gy1 - (Y0 - 2);       // rmbuf row index
    const int gym  = Y0 - 1 + R;           // m-row / output row
    const bool mrow = act && (R < 10);
    const bool orow = act && (R >= 1) && (R <= 8);

    const float* sv = src + (size_t)vol * NVOX;
    float*       dv = dst + (size_t)vol * NVOX;

    float xh1[8], xh2[8], Ah0[8], Ah1[8], Bh0[8], Bh1[8], mh0[8];
#pragma unroll
    for (int k = 0; k < 8; ++k) {
        Ah0[k] = FINF; Ah1[k] = FINF; Bh0[k] = -FINF; Bh1[k] = -FINF;
        xh1[k] = 0.f; xh2[k] = 0.f; mh0[k] = 0.f;
    }
    float s0 = 0.f, s1 = 0.f;

    for (int zo = zbeg - 4; zo < zend; ++zo) {
        const int zl = zo + 2;             // x plane loaded this step
        const int zm = zo + 1;             // m/B plane computed this step

        // ---------------- stage 1: load x(zl), rowmin_x, write rmbuf --------
        float xv[8];
        {
            const bool in1 = ((unsigned)zl < 160u) && ((unsigned)gy1 < 160u);
            if (act && in1) {
                const size_t base = (size_t)(zl * 160 + gy1) * 160 + x0;
                if (SRC == 0) {
                    ld8(sv + base, xv);
                } else if (vol < 2) {
                    ld8sig(net + (size_t)(vol * 2 + 0) * NVOX + base,
                           net + (size_t)(vol * 2 + 1) * NVOX + base, xv);
                } else {
                    ld8i(tgt + (size_t)(vol - 2) * NVOX + base, xv);
                }
            } else {
#pragma unroll
                for (int k = 0; k < 8; ++k) xv[k] = FINF;
            }
        }
        float vL = __shfl(xv[7], lane - 1); if (xt == 0)  vL = FINF;
        float vR = __shfl(xv[0], lane + 1); if (xt == 19) vR = FINF;
        {
            float r[8];
            r[0] = min3(vL, xv[0], xv[1]);
#pragma unroll
            for (int k = 1; k < 7; ++k) r[k] = min3(xv[k-1], xv[k], xv[k+1]);
            r[7] = min3(xv[6], xv[7], vR);
            if (act) st8(&rmbuf[ri][x0], r);
        }
        __syncthreads();

        // ---------------- stage 2: colmin->A, m=zmin(A), rowmax_x(m)->bmx ---
        float m_[8];
        if (mrow) {
            float p0[8], p1[8], p2[8];
            ld8(&rmbuf[R][x0], p0); ld8(&rmbuf[R+1][x0], p1); ld8(&rmbuf[R+2][x0], p2);
            const bool mv = ((unsigned)zm < 160u) && ((unsigned)gym < 160u);
#pragma unroll
            for (int k = 0; k < 8; ++k) {
                const float An = min3(p0[k], p1[k], p2[k]);
                float m = min3(An, Ah0[k], Ah1[k]);
                Ah0[k] = Ah1[k]; Ah1[k] = An;
                m_[k] = mv ? m : -FINF;
            }
        } else {
#pragma unroll
            for (int k = 0; k < 8; ++k) m_[k] = -FINF;
        }
        float mL = __shfl(m_[7], lane - 1); if (xt == 0)  mL = -FINF;
        float mR = __shfl(m_[0], lane + 1); if (xt == 19) mR = -FINF;
        if (mrow) {
            float bm[8];
            bm[0] = max3(mL, m_[0], m_[1]);
#pragma unroll
            for (int k = 1; k < 7; ++k) bm[k] = max3(m_[k-1], m_[k], m_[k+1]);
            bm[7] = max3(m_[6], m_[7], mR);
            st8(&bmx[R][x0], bm);
        }
        __syncthreads();

        // ---------------- stage 4: colmax->B(zm), emit plane zo -------------
        if (orow) {
            float q0[8], q1[8], q2[8], Bn[8];
            ld8(&bmx[R-1][x0], q0); ld8(&bmx[R][x0], q1); ld8(&bmx[R+1][x0], q2);
#pragma unroll
            for (int k = 0; k < 8; ++k) Bn[k] = max3(q0[k], q1[k], q2[k]);
            if (zo >= zbeg) {
                float o[8];
#pragma unroll
                for (int k = 0; k < 8; ++k) {
                    const float cm = max3(Bn[k], Bh0[k], Bh1[k]);
                    const float ct = fmaxf(cm - mh0[k], 0.f);
                    o[k] = fmaxf(xh1[k] - ct, 0.f);   // x(zo) lives in xh1 here
                }
                const size_t ob = (size_t)(zo * 160 + gym) * 160 + x0;
                if (SINK == 0) {
                    st8(dv + ob, o);
                } else if (vol < 2) {
                    float tg[8]; ld8i(tgt + (size_t)vol * NVOX + ob, tg);
#pragma unroll
                    for (int k = 0; k < 8; ++k) { s0 += o[k]; s1 += o[k] * tg[k]; }
                } else {
                    float fg[8];
                    ld8sig(net + (size_t)((vol - 2) * 2 + 0) * NVOX + ob,
                           net + (size_t)((vol - 2) * 2 + 1) * NVOX + ob, fg);
#pragma unroll
                    for (int k = 0; k < 8; ++k) { s0 += o[k]; s1 += o[k] * fg[k]; }
                }
            }
#pragma unroll
            for (int k = 0; k < 8; ++k) { Bh0[k] = Bh1[k]; Bh1[k] = Bn[k]; }
        }
#pragma unroll
        for (int k = 0; k < 8; ++k) {
            mh0[k] = m_[k];
            xh1[k] = xh2[k]; xh2[k] = xv[k];
        }
        // no barrier needed: next stage1 writes rmbuf (WAR covered by the
        // barrier after stage2's last rmbuf read); stage4 reads bmx, next
        // bmx write is after the next stage-1 barrier.
    }

    if (SINK == 1) {
#pragma unroll
        for (int off = 32; off > 0; off >>= 1) {
            s0 += __shfl_down(s0, off);
            s1 += __shfl_down(s1, off);
        }
        if (lane == 0) { red[0][wv] = s0; red[1][wv] = s1; }
        __syncthreads();
        if (threadIdx.x == 0) {
            const float t0 = red[0][0] + red[0][1] + red[0][2] + red[0][3];
            const float t1 = red[1][0] + red[1][1] + red[1][2] + red[1][3];
            const int i0 = (vol < 2) ? (vol * 4) : ((vol - 2) * 4 + 2);
            atomicAdd(&acc[i0],     t0);   // sum(skel)
            atomicAdd(&acc[i0 + 1], t1);   // sum(skel * other)
        }
    }
}

__global__ void zero_acc(float* acc) {
    if (threadIdx.x < 8) acc[threadIdx.x] = 0.f;
}

__global__ void finalize(const float* __restrict__ acc, float* __restrict__ out) {
    if (threadIdx.x == 0) {
        const float i0 = (acc[1] + 1.f) / (acc[0] + 1.f);
        const float t0 = (acc[3] + 1.f) / (acc[2] + 1.f);
        const float i1 = (acc[5] + 1.f) / (acc[4] + 1.f);
        const float t1 = (acc[7] + 1.f) / (acc[6] + 1.f);
        const float inter = i0 * t0 + i1 * t1;
        out[0] = -(2.f * inter / ((i0 + i1) + (t0 + t1)));
    }
}

// ---------------------------------------------------------------------------
extern "C" void kernel_launch(void* const* d_in, const int* in_sizes, int n_in,
                              void* d_out, int out_size, void* d_ws, size_t ws_size,
                              hipStream_t stream) {
    const float* net = (const float*)d_in[0];   // (2,2,160,160,160) f32
    const int*   tgt = (const int*)d_in[1];     // (2,1,160,160,160) int32
    float* bufA = (float*)d_ws;                 // 4 volumes
    float* bufB = bufA + (size_t)4 * NVOX;      // 4 volumes
    float* acc  = bufB + (size_t)4 * NVOX;      // 8 floats

    zero_acc<<<1, 64, 0, stream>>>(acc);

    const dim3 grid(20, NZC, 4);                // ychunks x zchunks x vols
    // iteration 1: fg/tg computed on the fly from inputs
    sweep<1, 0><<<grid, 256, 0, stream>>>(bufA, bufA, net, tgt, acc);
    // iterations 2..9
    float* s = bufA; float* d = bufB;
    for (int it = 1; it <= 8; ++it) {
        sweep<0, 0><<<grid, 256, 0, stream>>>(s, d, net, tgt, acc);
        float* t = s; s = d; d = t;
    }
    // iteration 10: fused reduction, no volume write
    sweep<0, 1><<<grid, 256, 0, stream>>>(s, d, net, tgt, acc);

    finalize<<<1, 64, 0, stream>>>(acc, (float*)d_out);
}

// Round 8
// 407.902 us; speedup vs baseline: 2.6979x; 1.1730x over previous
//
#include <hip/hip_runtime.h>
#include <math.h>

#define NVOX   (160*160*160)
#define PVOX   (160*160*5)        // packed u32 words per binary volume
#define ZCHUNK 10
#define NZC    16
#define FINF   INFINITY

typedef unsigned int u32;
typedef _Float16 half_t;
typedef __attribute__((ext_vector_type(8))) _Float16 h8;

__device__ __forceinline__ float min3(float a, float b, float c) { return fminf(a, fminf(b, c)); }
__device__ __forceinline__ float max3(float a, float b, float c) { return fmaxf(a, fmaxf(b, c)); }
__device__ __forceinline__ float sigd(float d) { return 1.0f / (1.0f + __expf(d)); }  // d = x0-x1

__device__ __forceinline__ void ld8f(const float* p, float* o) {
    float4 a = *(const float4*)p; float4 b = *(const float4*)(p + 4);
    o[0]=a.x; o[1]=a.y; o[2]=a.z; o[3]=a.w; o[4]=b.x; o[5]=b.y; o[6]=b.z; o[7]=b.w;
}
__device__ __forceinline__ void st8f(float* p, const float* o) {
    *(float4*)p       = make_float4(o[0], o[1], o[2], o[3]);
    *(float4*)(p + 4) = make_float4(o[4], o[5], o[6], o[7]);
}
__device__ __forceinline__ void ld8h(const half_t* p, float* o) {
    h8 v = *(const h8*)p;
#pragma unroll
    for (int k = 0; k < 8; ++k) o[k] = (float)v[k];
}
__device__ __forceinline__ void st8h(half_t* p, const float* o) {
    h8 v;
#pragma unroll
    for (int k = 0; k < 8; ++k) v[k] = (half_t)o[k];
    *(h8*)p = v;
}
__device__ __forceinline__ void ld8sig(const float* p0, const float* p1, float* o) {
    float a0[8], a1[8]; ld8f(p0, a0); ld8f(p1, a1);
#pragma unroll
    for (int k = 0; k < 8; ++k) o[k] = sigd(a0[k] - a1[k]);
}

// ---------------------------------------------------------------------------
// One skeletonization iteration; fg (fp16 continuous) and tg (bit-packed
// binary) share launches via blockIdx.z: z=0,1 -> fg batch b=z; z=2,3 -> tg
// batch b=z-2. Both paths are block-uniform (barriers legal).
//
// fg path: identical pipeline to the verified R7 kernel (z-plane sweep,
//   register pipelines Ah/Bh/mh/xh, LDS b128 row buffers, 2 barriers/plane),
//   but volumes stored fp16. At stage4 of step zo: xh1 = x(zo).
// tg path: same sweep on packed words; lanes xt<5 each own one u32 word
//   (32 x-voxels). min-pool = AND (pad 1), max-pool = OR (pad 0); x-direction
//   via shifts + neighbor word (lane shuffle); y via tiny LDS rows; z via
//   register pipeline. x' = x & ~(B & ~m). Binary is EXACT.
// SRC: 1 = derive from inputs (sigmoid / pack target, snapshot pO)
// SINK:1 = accumulate sums (fg: sum(skel), sum(skel*tgO via pO bits);
//          tg: store final packed + popcount)
// ---------------------------------------------------------------------------
template<int SRC, int SINK>
__global__ __launch_bounds__(256) void sweep(
        const half_t* __restrict__ src, half_t* __restrict__ dst,
        const u32* __restrict__ psrc, u32* __restrict__ pdst,
        const float* __restrict__ net, const int* __restrict__ tgt,
        u32* __restrict__ porig, float* __restrict__ acc)
{
    __shared__ float rmbuf[12][172];
    __shared__ float bmx[10][172];
    __shared__ u32   rmT[12][8];
    __shared__ u32   bmT[10][8];
    __shared__ float red[2][4];

    const int vol  = blockIdx.z;
    const int Y0   = blockIdx.x * 8;
    const int zbeg = blockIdx.y * ZCHUNK;
    const int zend = zbeg + ZCHUNK;
    const int lane = threadIdx.x & 63;
    const int wv   = threadIdx.x >> 6;
    const int r3   = lane / 20;
    const int xt   = lane - r3 * 20;
    const int R    = wv * 3 + r3;
    const bool act = (r3 < 3);
    const int gy1  = (R == 11) ? (Y0 - 2) : (Y0 - 1 + R);
    const int ri   = gy1 - (Y0 - 2);
    const int gym  = Y0 - 1 + R;
    const bool mrow = act && (R < 10);
    const bool orow = act && (R >= 1) && (R <= 8);

    if (vol >= 2) {
        // ================= tg path: packed binary morphology ================
        const int b = vol - 2;
        const u32* sv = psrc + (size_t)b * PVOX;
        u32*       dv = pdst + (size_t)b * PVOX;
        const bool wok = act && (xt < 5);

        u32 xh1 = 0, xh2 = 0, Ah0 = ~0u, Ah1 = ~0u, Bh0 = 0, Bh1 = 0, mh0 = 0;
        unsigned int cnt = 0;

        for (int zo = zbeg - 4; zo < zend; ++zo) {
            const int zl = zo + 2, zm = zo + 1;
            // stage 1: load/pack word, rowmin-x (AND), -> rmT
            u32 w = ~0u;
            if (wok && (unsigned)zl < 160u && (unsigned)gy1 < 160u) {
                if (SRC == 0) {
                    w = sv[((size_t)zl * 160 + gy1) * 5 + xt];
                } else {
                    w = 0;
                    const int* tp = tgt + (size_t)b * NVOX + ((size_t)zl * 160 + gy1) * 160 + xt * 32;
#pragma unroll
                    for (int q = 0; q < 8; ++q) {
                        int4 t4 = ((const int4*)tp)[q];
                        w |= (t4.x == 1 ? 1u : 0u) << (q * 4 + 0);
                        w |= (t4.y == 1 ? 1u : 0u) << (q * 4 + 1);
                        w |= (t4.z == 1 ? 1u : 0u) << (q * 4 + 2);
                        w |= (t4.w == 1 ? 1u : 0u) << (q * 4 + 3);
                    }
                    porig[(size_t)b * PVOX + ((size_t)zl * 160 + gy1) * 5 + xt] = w;
                }
            }
            u32 pw = __shfl(w, lane - 1); if (xt == 0) pw = ~0u;
            u32 nw = __shfl(w, lane + 1); if (xt == 4) nw = ~0u;
            if (wok) rmT[ri][xt] = ((w << 1) | (pw >> 31)) & w & ((w >> 1) | (nw << 31));
            __syncthreads();

            // stage 2: colmin (AND) -> A, m = z-AND, rowmax (OR) -> bmT
            u32 m = 0;
            if (mrow && xt < 5) {
                const u32 A = rmT[R][xt] & rmT[R + 1][xt] & rmT[R + 2][xt];
                m = A & Ah0 & Ah1;
                Ah0 = Ah1; Ah1 = A;
                if (!((unsigned)zm < 160u && (unsigned)gym < 160u)) m = 0;
            }
            u32 pm = __shfl(m, lane - 1); if (xt == 0) pm = 0;
            u32 nm = __shfl(m, lane + 1); if (xt == 4) nm = 0;
            if (mrow && xt < 5)
                bmT[R][xt] = ((m << 1) | (pm >> 31)) | m | ((m >> 1) | (nm << 31));
            __syncthreads();

            // stage 4: colmax (OR) -> B, emit plane zo
            if (orow && xt < 5) {
                const u32 B = bmT[R - 1][xt] | bmT[R][xt] | bmT[R + 1][xt];
                if (zo >= zbeg) {
                    const u32 cm = B | Bh0 | Bh1;
                    const u32 xo = xh1 & ~(cm & ~mh0);
                    const size_t ob = ((size_t)zo * 160 + gym) * 5 + xt;
                    dv[ob] = xo;                       // always write (pfinal)
                    if (SINK == 1) cnt += __popc(xo);
                }
                Bh0 = Bh1; Bh1 = B;
            }
            mh0 = m; xh1 = xh2; xh2 = w;
        }

        if (SINK == 1) {
            float s = (float)cnt;
#pragma unroll
            for (int off = 32; off > 0; off >>= 1) s += __shfl_down(s, off);
            if (lane == 0) red[0][wv] = s;
            __syncthreads();
            if (threadIdx.x == 0)
                atomicAdd(&acc[b * 4 + 2], red[0][0] + red[0][1] + red[0][2] + red[0][3]);
        }
        return;
    }

    // ==================== fg path: fp16 continuous sweep ====================
    const int b  = vol;
    const int x0 = xt * 8;
    const half_t* sv = src + (size_t)b * NVOX;
    half_t*       dv = dst + (size_t)b * NVOX;

    float xh1[8], xh2[8], Ah0[8], Ah1[8], Bh0[8], Bh1[8], mh0[8];
#pragma unroll
    for (int k = 0; k < 8; ++k) {
        Ah0[k] = FINF; Ah1[k] = FINF; Bh0[k] = -FINF; Bh1[k] = -FINF;
        xh1[k] = 0.f; xh2[k] = 0.f; mh0[k] = 0.f;
    }
    float s0 = 0.f, s1 = 0.f;

    for (int zo = zbeg - 4; zo < zend; ++zo) {
        const int zl = zo + 2, zm = zo + 1;

        // stage 1: load x(zl), rowmin-x, -> rmbuf
        float xv[8];
        {
            const bool in1 = ((unsigned)zl < 160u) && ((unsigned)gy1 < 160u);
            if (act && in1) {
                const size_t base = ((size_t)zl * 160 + gy1) * 160 + x0;
                if (SRC == 0) ld8h(sv + base, xv);
                else ld8sig(net + (size_t)(b * 2 + 0) * NVOX + base,
                            net + (size_t)(b * 2 + 1) * NVOX + base, xv);
            } else {
#pragma unroll
                for (int k = 0; k < 8; ++k) xv[k] = FINF;
            }
        }
        float vL = __shfl(xv[7], lane - 1); if (xt == 0)  vL = FINF;
        float vR = __shfl(xv[0], lane + 1); if (xt == 19) vR = FINF;
        {
            float r[8];
            r[0] = min3(vL, xv[0], xv[1]);
#pragma unroll
            for (int k = 1; k < 7; ++k) r[k] = min3(xv[k-1], xv[k], xv[k+1]);
            r[7] = min3(xv[6], xv[7], vR);
            if (act) st8f(&rmbuf[ri][x0], r);
        }
        __syncthreads();

        // stage 2: colmin->A, m = z-min, rowmax->bmx
        float m_[8];
        if (mrow) {
            float p0[8], p1[8], p2[8];
            ld8f(&rmbuf[R][x0], p0); ld8f(&rmbuf[R+1][x0], p1); ld8f(&rmbuf[R+2][x0], p2);
            const bool mv = ((unsigned)zm < 160u) && ((unsigned)gym < 160u);
#pragma unroll
            for (int k = 0; k < 8; ++k) {
                const float An = min3(p0[k], p1[k], p2[k]);
                float m = min3(An, Ah0[k], Ah1[k]);
                Ah0[k] = Ah1[k]; Ah1[k] = An;
                m_[k] = mv ? m : -FINF;
            }
        } else {
#pragma unroll
            for (int k = 0; k < 8; ++k) m_[k] = -FINF;
        }
        float mL = __shfl(m_[7], lane - 1); if (xt == 0)  mL = -FINF;
        float mR = __shfl(m_[0], lane + 1); if (xt == 19) mR = -FINF;
        if (mrow) {
            float bm[8];
            bm[0] = max3(mL, m_[0], m_[1]);
#pragma unroll
            for (int k = 1; k < 7; ++k) bm[k] = max3(m_[k-1], m_[k], m_[k+1]);
            bm[7] = max3(m_[6], m_[7], mR);
            st8f(&bmx[R][x0], bm);
        }
        __syncthreads();

        // stage 4: colmax->B(zm), emit plane zo (x(zo) lives in xh1)
        if (orow) {
            float q0[8], q1[8], q2[8], Bn[8];
            ld8f(&bmx[R-1][x0], q0); ld8f(&bmx[R][x0], q1); ld8f(&bmx[R+1][x0], q2);
#pragma unroll
            for (int k = 0; k < 8; ++k) Bn[k] = max3(q0[k], q1[k], q2[k]);
            if (zo >= zbeg) {
                float o[8];
#pragma unroll
                for (int k = 0; k < 8; ++k) {
                    const float cm = max3(Bn[k], Bh0[k], Bh1[k]);
                    const float ct = fmaxf(cm - mh0[k], 0.f);
                    o[k] = fmaxf(xh1[k] - ct, 0.f);
                }
                const size_t ob = ((size_t)zo * 160 + gym) * 160 + x0;
                if (SINK == 0) {
                    st8h(dv + ob, o);
                } else {
                    const u32 w = porig[(size_t)b * PVOX + ((size_t)zo * 160 + gym) * 5 + (x0 >> 5)];
                    const int sh = x0 & 31;
#pragma unroll
                    for (int k = 0; k < 8; ++k) {
                        s0 += o[k];
                        s1 += ((w >> (sh + k)) & 1u) ? o[k] : 0.f;
                    }
                }
            }
#pragma unroll
            for (int k = 0; k < 8; ++k) { Bh0[k] = Bh1[k]; Bh1[k] = Bn[k]; }
        }
#pragma unroll
        for (int k = 0; k < 8; ++k) {
            mh0[k] = m_[k];
            xh1[k] = xh2[k]; xh2[k] = xv[k];
        }
    }

    if (SINK == 1) {
#pragma unroll
        for (int off = 32; off > 0; off >>= 1) {
            s0 += __shfl_down(s0, off);
            s1 += __shfl_down(s1, off);
        }
        if (lane == 0) { red[0][wv] = s0; red[1][wv] = s1; }
        __syncthreads();
        if (threadIdx.x == 0) {
            atomicAdd(&acc[b * 4 + 0], red[0][0] + red[0][1] + red[0][2] + red[0][3]);
            atomicAdd(&acc[b * 4 + 1], red[1][0] + red[1][1] + red[1][2] + red[1][3]);
        }
    }
}

// sum(skel_tg * fg_orig): stream net once, gate by packed final-tg bits
__global__ __launch_bounds__(256) void reduce_tf(const float* __restrict__ net,
                                                 const u32* __restrict__ pfin,
                                                 float* __restrict__ acc) {
    const int b = blockIdx.y;
    const float* n0 = net + (size_t)(b * 2 + 0) * NVOX;
    const float* n1 = net + (size_t)(b * 2 + 1) * NVOX;
    const u32*   pf = pfin + (size_t)b * PVOX;
    float s = 0.f;
    for (int i = (blockIdx.x * 256 + threadIdx.x) * 8; i < NVOX; i += gridDim.x * 256 * 8) {
        const u32 byte = (pf[i >> 5] >> (i & 31)) & 0xffu;
        if (byte) {
            float a0[8], a1[8];
            ld8f(n0 + i, a0); ld8f(n1 + i, a1);
#pragma unroll
            for (int k = 0; k < 8; ++k)
                if ((byte >> k) & 1u) s += sigd(a0[k] - a1[k]);
        }
    }
#pragma unroll
    for (int off = 32; off > 0; off >>= 1) s += __shfl_down(s, off);
    __shared__ float part[4];
    const int wv = threadIdx.x >> 6, lane = threadIdx.x & 63;
    if (lane == 0) part[wv] = s;
    __syncthreads();
    if (threadIdx.x == 0) atomicAdd(&acc[b * 4 + 3], part[0] + part[1] + part[2] + part[3]);
}

__global__ void zero_acc(float* acc) {
    if (threadIdx.x < 8) acc[threadIdx.x] = 0.f;
}

__global__ void finalize(const float* __restrict__ acc, float* __restrict__ out) {
    if (threadIdx.x == 0) {
        const float i0 = (acc[1] + 1.f) / (acc[0] + 1.f);
        const float t0 = (acc[3] + 1.f) / (acc[2] + 1.f);
        const float i1 = (acc[5] + 1.f) / (acc[4] + 1.f);
        const float t1 = (acc[7] + 1.f) / (acc[6] + 1.f);
        const float inter = i0 * t0 + i1 * t1;
        out[0] = -(2.f * inter / ((i0 + i1) + (t0 + t1)));
    }
}

// ---------------------------------------------------------------------------
extern "C" void kernel_launch(void* const* d_in, const int* in_sizes, int n_in,
                              void* d_out, int out_size, void* d_ws, size_t ws_size,
                              hipStream_t stream) {
    const float* net = (const float*)d_in[0];   // (2,2,160,160,160) f32
    const int*   tgt = (const int*)d_in[1];     // (2,1,160,160,160) int32
    half_t* bufA = (half_t*)d_ws;               // 2 fp16 volumes
    half_t* bufB = bufA + (size_t)2 * NVOX;
    u32* pA = (u32*)(bufB + (size_t)2 * NVOX);  // 2 packed volumes
    u32* pB = pA + (size_t)2 * PVOX;
    u32* pO = pB + (size_t)2 * PVOX;            // packed original target
    float* acc = (float*)(pO + (size_t)2 * PVOX);

    zero_acc<<<1, 64, 0, stream>>>(acc);

    const dim3 grid(20, NZC, 4);                // y-tiles x z-chunks x (2 fg + 2 tg)
    sweep<1, 0><<<grid, 256, 0, stream>>>(bufB, bufA, pB, pA, net, tgt, pO, acc);
    half_t* s = bufA; half_t* d = bufB;
    u32* ps = pA; u32* pd = pB;
    for (int it = 1; it <= 8; ++it) {
        sweep<0, 0><<<grid, 256, 0, stream>>>(s, d, ps, pd, net, tgt, pO, acc);
        half_t* t = s; s = d; d = t;
        u32* q = ps; ps = pd; pd = q;
    }
    sweep<0, 1><<<grid, 256, 0, stream>>>(s, d, ps, pd, net, tgt, pO, acc);

    reduce_tf<<<dim3(512, 2), 256, 0, stream>>>(net, pd, acc);
    finalize<<<1, 64, 0, stream>>>(acc, (float*)d_out);
}